// Round 8
// baseline (4426.027 us; speedup 1.0000x reference)
//
#include <hip/hip_runtime.h>
#include <hip/hip_cooperative_groups.h>
#include <stdint.h>

typedef unsigned int uint;
typedef unsigned long long ull;
typedef __attribute__((ext_vector_type(8))) short short8;
typedef __attribute__((ext_vector_type(4))) float f32x4;

#define AS1 __attribute__((address_space(1)))
#define AS3 __attribute__((address_space(3)))

__device__ __forceinline__ unsigned short f2bf(float f) {
  uint u = __float_as_uint(f);
  u += 0x7fffu + ((u >> 16) & 1u);
  return (unsigned short)(u >> 16);
}
__device__ __forceinline__ float bfl(unsigned short s) {
  return __uint_as_float(((uint)s) << 16);
}

// ---------------- build kernels ----------------

// A[dir][m=t*8+b][e] = bf16(x or x_rev), 2 x 4096 x 1024
__global__ __launch_bounds__(256) void k_build_A(const float* __restrict__ x,
                                                 const int* __restrict__ lengths,
                                                 unsigned short* __restrict__ A) {
  int idx = blockIdx.x * 256 + threadIdx.x;   // float4 units, 2*1Mi total
  int dir = idx >> 20;
  int r = idx & 1048575;
  int m = r >> 8;
  int e4 = r & 255;
  int t = m >> 3, b = m & 7;
  int st = t;
  if (dir) { int len = lengths[b]; st = (t < len) ? (len - 1 - t) : t; }
  float4 v = *(const float4*)&x[((size_t)b * 512 + st) * 1024 + e4 * 4];
  ushort4 o;
  o.x = f2bf(v.x); o.y = f2bf(v.y); o.z = f2bf(v.z); o.w = f2bf(v.w);
  *(ushort4*)&A[(size_t)dir * 4194304 + (size_t)m * 1024 + e4 * 4] = o;
}

// Wp[dir][j][e] = bf16(W_ih)
__global__ __launch_bounds__(256) void k_cast_wih(const float* __restrict__ Wf,
                                                  const float* __restrict__ Wb,
                                                  unsigned short* __restrict__ Wp) {
  int idx = blockIdx.x * 256 + threadIdx.x;
  int dir = idx >> 20;
  int r = idx & 1048575;
  const float* src = dir ? Wb : Wf;
  float4 v = *(const float4*)&src[(size_t)r * 4];
  ushort4 o;
  o.x = f2bf(v.x); o.y = f2bf(v.y); o.z = f2bf(v.z); o.w = f2bf(v.w);
  *(ushort4*)&Wp[(size_t)dir * 4194304 + (size_t)r * 4] = o;
}

// WF: W_hh in MFMA B-fragment order, per (dir, mc) slice of 32 j-rows.
// gtid = lane(6) | f(6) | mc(7) | dir(1); f = kt*2+nt
// B[n_local = nt*16+(lane&15)][k = kt*32+(lane>>4)*8 + v], v<8
// j = (n_local>>3)*1024 + mc*8 + (n_local&7)
__global__ __launch_bounds__(256) void k_build_wf(const float* __restrict__ Wf,
                                                  const float* __restrict__ Wb,
                                                  unsigned short* __restrict__ WF) {
  int gtid = blockIdx.x * 256 + threadIdx.x;   // 2^20
  int lane = gtid & 63;
  int f    = (gtid >> 6) & 63;
  int mc   = (gtid >> 12) & 127;
  int dir  = (gtid >> 19) & 1;
  int kt = f >> 1, nt = f & 1;
  int n_local = nt * 16 + (lane & 15);
  int j = (n_local >> 3) * 1024 + mc * 8 + (n_local & 7);
  int k0 = kt * 32 + (lane >> 4) * 8;
  const float* src = dir ? Wb : Wf;
  const float* s = &src[(size_t)j * 1024 + k0];
  float4 v0 = *(const float4*)s;
  float4 v1 = *(const float4*)(s + 4);
  ushort4 oa, ob;
  oa.x = f2bf(v0.x); oa.y = f2bf(v0.y); oa.z = f2bf(v0.z); oa.w = f2bf(v0.w);
  ob.x = f2bf(v1.x); ob.y = f2bf(v1.y); ob.z = f2bf(v1.z); ob.w = f2bf(v1.w);
  *(ushort4*)&WF[(size_t)gtid * 8] = oa;
  *(ushort4*)&WF[(size_t)gtid * 8 + 4] = ob;
}

// WET[e][k] = W_emit[k][e]  (fp32)
__global__ __launch_bounds__(256) void k_build_wet(const float* __restrict__ We,
                                                   float* __restrict__ WET) {
  int idx = blockIdx.x * 256 + threadIdx.x;  // 32768
  int e = idx >> 4, k = idx & 15;
  WET[(size_t)e * 16 + k] = We[(size_t)k * 2048 + e];
}

// ---------------- projection GEMM (bf16 MFMA): P[dir][m][j] = A @ W_ih^T + b ----------------
__global__ __launch_bounds__(256) void k_proj(const unsigned short* __restrict__ A,
                                              const unsigned short* __restrict__ Wp,
                                              const float* __restrict__ bfv,
                                              const float* __restrict__ bbv,
                                              unsigned short* __restrict__ P) {
  const int dir = blockIdx.z;
  const unsigned short* Ad = A + (size_t)dir * 4194304;
  const unsigned short* Wd = Wp + (size_t)dir * 4194304;
  const float* bias = dir ? bbv : bfv;
  unsigned short* Pd = P + (size_t)dir * 16777216;
  const int bm = blockIdx.x * 128;
  const int bn = blockIdx.y * 128;
  __shared__ unsigned short As[128 * 32];
  __shared__ unsigned short Bs[128 * 32];
  const int tid = threadIdx.x;
  const int w = tid >> 6, lane = tid & 63;
  const int wm = (w >> 1) * 64, wn = (w & 1) * 64;
  const int q = lane >> 4, rr = lane & 15;

  f32x4 acc[4][4];
#pragma unroll
  for (int i = 0; i < 4; ++i)
#pragma unroll
    for (int j = 0; j < 4; ++j) acc[i][j] = (f32x4){0.f, 0.f, 0.f, 0.f};

  for (int k0 = 0; k0 < 1024; k0 += 32) {
#pragma unroll
    for (int i = 0; i < 2; ++i) {
      int c = i * 256 + tid;
      int row = c >> 2, col = (c & 3) * 8;
      const unsigned short* ga = Ad + (size_t)(bm + row) * 1024 + k0 + col;
      const unsigned short* gb = Wd + (size_t)(bn + row) * 1024 + k0 + col;
      __builtin_amdgcn_global_load_lds((const AS1 void*)ga,
                                       (AS3 void*)&As[(i * 256 + w * 64) * 8], 16, 0, 0);
      __builtin_amdgcn_global_load_lds((const AS1 void*)gb,
                                       (AS3 void*)&Bs[(i * 256 + w * 64) * 8], 16, 0, 0);
    }
    __syncthreads();
    short8 av[4], bv[4];
#pragma unroll
    for (int i = 0; i < 4; ++i)
      av[i] = *(const short8*)&As[(wm + i * 16 + rr) * 32 + q * 8];
#pragma unroll
    for (int j = 0; j < 4; ++j)
      bv[j] = *(const short8*)&Bs[(wn + j * 16 + rr) * 32 + q * 8];
#pragma unroll
    for (int i = 0; i < 4; ++i)
#pragma unroll
      for (int j = 0; j < 4; ++j)
        acc[i][j] = __builtin_amdgcn_mfma_f32_16x16x32_bf16(av[i], bv[j], acc[i][j], 0, 0, 0);
    __syncthreads();
  }
#pragma unroll
  for (int i = 0; i < 4; ++i)
#pragma unroll
    for (int j = 0; j < 4; ++j)
#pragma unroll
      for (int reg = 0; reg < 4; ++reg) {
        int row = wm + i * 16 + q * 4 + reg;
        int col = wn + j * 16 + rr;
        float vv = acc[i][j][reg] + bias[bn + col];
        Pd[(size_t)(bm + row) * 4096 + bn + col] = f2bf(vv);
      }
}

// ---------------- persistent recurrence: 256 blocks, W in LDS, TAGGED exchange ----------
// R5 structure (dir = bid&1, mc = bid>>1 < 128, 32 j-rows = 4 gates x 8 hidden,
// MFMA on waves 1,2, 1-cell epilogue on wave 0) with the flag+ack exchange replaced by
// self-tagged u64 words: hgT[buf][dir][b][512] = (t<<32)|bf16x2, relaxed agent atomics.
// Publish is fire-and-forget (no s_waitcnt, no flag). Consumers bulk-load 4096 words
// coalesced (16/thread) and retry only stale words. WAR across the 2-deep ping-pong is
// safe: publishing t+1 requires having read all h[t], which requires all blocks
// published t, which requires all blocks finished reading t-1 from that slot.
// Poison 0xAAAAAAAA never equals a tag (0..511) -> no init needed.
// LDS: w_lds 65536 B | h_lds 8 x 1056 shorts = 16896 B | gl 32x9 f32 = 1152 B
__global__ __launch_bounds__(256, 1) void k_rec(const unsigned short* __restrict__ WF,
                                                const unsigned short* __restrict__ P,
                                                const int* __restrict__ lengths,
                                                ull* __restrict__ hgT,    // [2][2][8][512]
                                                float* __restrict__ h_seq) {
  extern __shared__ char smem[];
  unsigned short* w_lds = (unsigned short*)smem;             // 32768 shorts = 65536 B
  unsigned short* h_lds = (unsigned short*)(smem + 65536);   // 8 x 1056 shorts
  float* gl = (float*)(smem + 82432);                        // 32 x 9

  const int bid = blockIdx.x;
  const int dir = bid & 1;
  const int mc  = bid >> 1;
  const int tid = threadIdx.x;
  const int w   = tid >> 6, lane = tid & 63;
  const int q   = lane >> 4;
  const int nt  = w - 1;                 // waves 1,2 -> n-tiles 0,1

  // ---- stage W slice into LDS (once): 32768 shorts = 4096 uint4 ----
  {
    const uint4* src = (const uint4*)(WF + (size_t)(dir * 128 + mc) * 32768);
    uint4* dst = (uint4*)w_lds;
#pragma unroll
    for (int r_ = 0; r_ < 16; ++r_) dst[tid + 256 * r_] = src[tid + 256 * r_];
  }

  // epilogue identity (tid<64): b = tid>>3, r = tid&7
  const int eb = tid >> 3, er = tid & 7;
  const int len_e = (tid < 64) ? lengths[eb] : 0;
  float c_reg = 0.f, h_reg = 0.f;
  __syncthreads();

  for (int t = 0; t < 512; ++t) {
    // ---- P prefetch (raw ushorts; converted only in epilogue) ----
    unsigned short pv0 = 0, pv1 = 0, pv2 = 0, pv3 = 0;
    if (tid < 64) {
      const unsigned short* prow =
          P + (size_t)dir * 16777216 + (size_t)(t * 8 + eb) * 4096 + mc * 8 + er;
      pv0 = prow[0]; pv1 = prow[1024]; pv2 = prow[2048]; pv3 = prow[3072];
    }

    if (t > 0) {
      // ---- speculative tagged bulk load of h[t-1] (coalesced, retry stale) ----
      const ull* src = hgT + (size_t)(((t - 1) & 1) * 2 + dir) * 4096;
      ull vals[16];
#pragma unroll
      for (int i = 0; i < 16; ++i)
        vals[i] = __hip_atomic_load(&src[tid + 256 * i], __ATOMIC_RELAXED,
                                    __HIP_MEMORY_SCOPE_AGENT);
      const uint need = (uint)(t - 1);
      uint ok = 0;
      while (ok != 0xFFFFu) {
#pragma unroll
        for (int i = 0; i < 16; ++i) {
          if (!(ok & (1u << i))) {
            if ((uint)(vals[i] >> 32) == need) ok |= (1u << i);
            else vals[i] = __hip_atomic_load(&src[tid + 256 * i], __ATOMIC_RELAXED,
                                             __HIP_MEMORY_SCOPE_AGENT);
          }
        }
      }
      // ---- write to LDS (strip tags): word u -> batch u>>9, hidden-pair u&511 ----
#pragma unroll
      for (int i = 0; i < 16; ++i) {
        int u = tid + 256 * i;
        *(uint*)&h_lds[(u >> 9) * 1056 + (u & 511) * 2] = (uint)vals[i];
      }
      __syncthreads();                                   // B2: h_lds ready
      // ---- MFMA: waves 1,2, 4 interleaved accumulators ----
      if (nt == 0 || nt == 1) {
        f32x4 a0 = (f32x4){0.f,0.f,0.f,0.f}, a1 = a0, a2 = a0, a3 = a0;
#pragma unroll
        for (int kt = 0; kt < 32; kt += 4) {
          short8 v0 = *(const short8*)&h_lds[(lane & 7) * 1056 + (kt + 0) * 32 + q * 8];
          short8 v1 = *(const short8*)&h_lds[(lane & 7) * 1056 + (kt + 1) * 32 + q * 8];
          short8 v2 = *(const short8*)&h_lds[(lane & 7) * 1056 + (kt + 2) * 32 + q * 8];
          short8 v3 = *(const short8*)&h_lds[(lane & 7) * 1056 + (kt + 3) * 32 + q * 8];
          short8 b0 = *(const short8*)&w_lds[((kt + 0) * 2 + nt) * 512 + lane * 8];
          short8 b1 = *(const short8*)&w_lds[((kt + 1) * 2 + nt) * 512 + lane * 8];
          short8 b2 = *(const short8*)&w_lds[((kt + 2) * 2 + nt) * 512 + lane * 8];
          short8 b3 = *(const short8*)&w_lds[((kt + 3) * 2 + nt) * 512 + lane * 8];
          a0 = __builtin_amdgcn_mfma_f32_16x16x32_bf16(v0, b0, a0, 0, 0, 0);
          a1 = __builtin_amdgcn_mfma_f32_16x16x32_bf16(v1, b1, a1, 0, 0, 0);
          a2 = __builtin_amdgcn_mfma_f32_16x16x32_bf16(v2, b2, a2, 0, 0, 0);
          a3 = __builtin_amdgcn_mfma_f32_16x16x32_bf16(v3, b3, a3, 0, 0, 0);
        }
        a0 += a1; a2 += a3; a0 += a2;
        if (q < 2) {
#pragma unroll
          for (int reg = 0; reg < 4; ++reg)
            gl[(nt * 16 + (lane & 15)) * 9 + q * 4 + reg] = a0[reg];
        }
      }
    }
    __syncthreads();                                     // B3: gl ready (or t==0)

    // ---- epilogue: wave 0, one (b, m) cell per thread ----
    if (tid < 64 && t < len_e) {
      float g0 = (t > 0) ? gl[(0 * 8 + er) * 9 + eb] : 0.f;
      float g1 = (t > 0) ? gl[(1 * 8 + er) * 9 + eb] : 0.f;
      float g2 = (t > 0) ? gl[(2 * 8 + er) * 9 + eb] : 0.f;
      float g3 = (t > 0) ? gl[(3 * 8 + er) * 9 + eb] : 0.f;
      float gi = g0 + bfl(pv0);
      float gf = g1 + bfl(pv1);
      float gg = g2 + bfl(pv2);
      float go = g3 + bfl(pv3);
      float si = 1.f / (1.f + __expf(-gi));
      float sf = 1.f / (1.f + __expf(-gf));
      float so = 1.f / (1.f + __expf(-go));
      float tg = tanhf(gg);
      float cn = sf * c_reg + si * tg;
      float hn = so * tanhf(cn);
      c_reg = cn;
      h_reg = hn;
      h_seq[((size_t)(dir * 512 + t) * 8 + eb) * 1024 + mc * 8 + er] = hn;
    }
    // ---- publish h[t] as self-tagged words: fire-and-forget, no ack, no flag ----
    if (tid < 64) {
      float hpart = __shfl_xor(h_reg, 1);
      if (!(tid & 1)) {
        uint d = (uint)f2bf(h_reg) | ((uint)f2bf(hpart) << 16);
        ull word = ((ull)(uint)t << 32) | (ull)d;
        ull* dst = hgT + (size_t)((t & 1) * 2 + dir) * 4096
                   + (size_t)eb * 512 + mc * 4 + (er >> 1);
        __hip_atomic_store(dst, word, __ATOMIC_RELAXED, __HIP_MEMORY_SCOPE_AGENT);
      }
    }
  }
}

// ---------------- emissions: emit[t*8+b][k] = [hf, hb(rev)] @ W_emit^T + b_emit ----------------
__global__ __launch_bounds__(64) void k_emit(const float* __restrict__ h_seq,
    const float* __restrict__ WET, const float* __restrict__ b_emit,
    const int* __restrict__ lengths, float* __restrict__ emit) {
  __shared__ float hl[4][2048];
  const int tid = threadIdx.x;
  const int p0 = blockIdx.x * 4;
  for (int i = 0; i < 32; ++i) {
    int idx = tid + i * 64;          // float4 index 0..2047
    int pl = idx >> 9;
    int r = idx & 511;
    int p = p0 + pl;
    int t = p >> 3, b = p & 7;
    int len = lengths[b];
    float4 v = make_float4(0.f, 0.f, 0.f, 0.f);
    if (t < len) {
      if (r < 256) {
        v = *(const float4*)&h_seq[((size_t)t * 8 + b) * 1024 + r * 4];
      } else {
        int tr = len - 1 - t;
        v = *(const float4*)&h_seq[((size_t)(512 + tr) * 8 + b) * 1024 + (r - 256) * 4];
      }
    }
    *(float4*)&hl[pl][r * 4] = v;
  }
  __syncthreads();
  const int k = tid & 15, pl = tid >> 4;
  const int p = p0 + pl;
  const int t = p >> 3, b = p & 7;
  const int len = lengths[b];
  float acc = 0.f;
  if (t < len) {
    const float* hrow = hl[pl];
#pragma unroll 4
    for (int e4 = 0; e4 < 512; ++e4) {
      float4 h4 = *(const float4*)&hrow[e4 * 4];
      acc += h4.x * WET[(e4 * 4 + 0) * 16 + k]
           + h4.y * WET[(e4 * 4 + 1) * 16 + k]
           + h4.z * WET[(e4 * 4 + 2) * 16 + k]
           + h4.w * WET[(e4 * 4 + 3) * 16 + k];
    }
    acc += b_emit[k];
  }
  emit[(size_t)p * 16 + k] = (t < len) ? acc : 0.f;
}

// ---------------- CRF: gold score + forward algorithm, out[b] = logZ - total ----------------
__global__ __launch_bounds__(128) void k_crf(const float* __restrict__ emit,
    const int* __restrict__ tags, const int* __restrict__ lengths,
    const float* __restrict__ trans, float* __restrict__ out) {
  __shared__ float d_lds[8][17];
  __shared__ float tot[8][17];
  __shared__ float totb[8];
  const int tid = threadIdx.x;
  const int b = tid >> 4, k = tid & 15;
  const int len = lengths[b];

  float part = 0.f;
  for (int t = k; t < 512; t += 16) {
    if (t < len) {
      int tg = tags[b * 512 + t];
      part += emit[((size_t)t * 8 + b) * 16 + tg];
      if (t >= 1) part += trans[tags[b * 512 + t - 1] * 16 + tg];
    }
  }
  tot[b][k] = part;

  float trc[16];
#pragma unroll
  for (int i = 0; i < 16; ++i) trc[i] = trans[i * 16 + k];
  d_lds[b][k] = emit[b * 16 + k];
  __syncthreads();
  if (k == 0) {
    float s = 0.f;
    for (int i = 0; i < 16; ++i) s += tot[b][i];
    totb[b] = s;
  }
  __syncthreads();

  for (int t = 1; t < 512; ++t) {
    float nd = 0.f;
    bool upd = (t < len);
    if (upd) {
      float mx = -3.0e38f;
      float v[16];
#pragma unroll
      for (int i = 0; i < 16; ++i) { v[i] = d_lds[b][i] + trc[i]; mx = fmaxf(mx, v[i]); }
      float s = 0.f;
#pragma unroll
      for (int i = 0; i < 16; ++i) s += __expf(v[i] - mx);
      nd = mx + __logf(s) + emit[((size_t)t * 8 + b) * 16 + k];
    }
    __syncthreads();
    if (upd) d_lds[b][k] = nd;
    __syncthreads();
  }

  if (k == 0) {
    float mx = -3.0e38f;
    for (int i = 0; i < 16; ++i) mx = fmaxf(mx, d_lds[b][i]);
    float s = 0.f;
    for (int i = 0; i < 16; ++i) s += __expf(d_lds[b][i] - mx);
    out[b] = (mx + __logf(s)) - totb[b];
  }
}

extern "C" void kernel_launch(void* const* d_in, const int* in_sizes, int n_in,
                              void* d_out, int out_size, void* d_ws, size_t ws_size,
                              hipStream_t stream) {
  const float* x       = (const float*)d_in[0];
  const int*   tags    = (const int*)d_in[1];
  const int*   lengths = (const int*)d_in[2];
  const float* W_ih_f  = (const float*)d_in[3];
  const float* W_hh_f  = (const float*)d_in[4];
  const float* b_f     = (const float*)d_in[5];
  const float* W_ih_b  = (const float*)d_in[6];
  const float* W_hh_b  = (const float*)d_in[7];
  const float* b_b     = (const float*)d_in[8];
  const float* W_emit  = (const float*)d_in[9];
  const float* b_emit  = (const float*)d_in[10];
  const float* trans   = (const float*)d_in[11];
  float* out = (float*)d_out;
  (void)in_sizes; (void)n_in; (void)out_size; (void)ws_size;

  char* ws = (char*)d_ws;
  unsigned short* A    = (unsigned short*)ws; ws += 16777216;   // 2 x 4096 x 1024 bf16
  unsigned short* Wp   = (unsigned short*)ws; ws += 16777216;   // 2 x 4096 x 1024 bf16
  unsigned short* WF   = (unsigned short*)ws; ws += 16777216;   // MFMA-frag-ordered W_hh
  unsigned short* P    = (unsigned short*)ws; ws += 67108864;   // 2 x 4096 x 4096 bf16
  float* h_seq = (float*)ws; ws += 33554432;                    // 2 x 512 x 8 x 1024 f32
  ull*   hgT   = (ull*)ws;   ws += 131072;                      // 2buf x 2dir x 4096 u64
  float* emit  = (float*)ws; ws += 262144;
  float* WET   = (float*)ws; ws += 131072;

  // hgT needs NO init: 0xAA poison tag (0xAAAAAAAA) never matches a real tag 0..511.

  static int attr_done = 0;
  if (!attr_done) {
    hipFuncSetAttribute((const void*)k_rec,
                        hipFuncAttributeMaxDynamicSharedMemorySize, 83584);
    attr_done = 1;
  }

  k_build_A<<<8192, 256, 0, stream>>>(x, lengths, A);
  k_cast_wih<<<8192, 256, 0, stream>>>(W_ih_f, W_ih_b, Wp);
  k_build_wf<<<4096, 256, 0, stream>>>(W_hh_f, W_hh_b, WF);
  k_build_wet<<<128, 256, 0, stream>>>(W_emit, WET);
  k_proj<<<dim3(32, 32, 2), 256, 0, stream>>>(A, Wp, b_f, b_b, P);

  {
    const unsigned short* wf = WF;
    const unsigned short* pp = P;
    const int* ll = lengths;
    ull* hgp = hgT; float* hs = h_seq;
    void* args[] = { &wf, &pp, &ll, &hgp, &hs };
    hipLaunchCooperativeKernel((const void*)k_rec, dim3(256), dim3(256),
                               args, 83584, stream);
  }

  k_emit<<<1024, 64, 0, stream>>>(h_seq, WET, b_emit, lengths, emit);
  k_crf<<<1, 128, 0, stream>>>(emit, tags, lengths, trans, out);
}

// Round 9
// 2944.106 us; speedup vs baseline: 1.5034x; 1.5034x over previous
//
#include <hip/hip_runtime.h>
#include <hip/hip_cooperative_groups.h>
#include <stdint.h>

typedef unsigned int uint;
typedef unsigned long long ull;
typedef __attribute__((ext_vector_type(8))) short short8;
typedef __attribute__((ext_vector_type(4))) float f32x4;

#define AS1 __attribute__((address_space(1)))
#define AS3 __attribute__((address_space(3)))

__device__ __forceinline__ unsigned short f2bf(float f) {
  uint u = __float_as_uint(f);
  u += 0x7fffu + ((u >> 16) & 1u);
  return (unsigned short)(u >> 16);
}
__device__ __forceinline__ float bfl(unsigned short s) {
  return __uint_as_float(((uint)s) << 16);
}

// ---------------- build kernels ----------------

// A[dir][m=t*8+b][e] = bf16(x or x_rev), 2 x 4096 x 1024
__global__ __launch_bounds__(256) void k_build_A(const float* __restrict__ x,
                                                 const int* __restrict__ lengths,
                                                 unsigned short* __restrict__ A) {
  int idx = blockIdx.x * 256 + threadIdx.x;   // float4 units, 2*1Mi total
  int dir = idx >> 20;
  int r = idx & 1048575;
  int m = r >> 8;
  int e4 = r & 255;
  int t = m >> 3, b = m & 7;
  int st = t;
  if (dir) { int len = lengths[b]; st = (t < len) ? (len - 1 - t) : t; }
  float4 v = *(const float4*)&x[((size_t)b * 512 + st) * 1024 + e4 * 4];
  ushort4 o;
  o.x = f2bf(v.x); o.y = f2bf(v.y); o.z = f2bf(v.z); o.w = f2bf(v.w);
  *(ushort4*)&A[(size_t)dir * 4194304 + (size_t)m * 1024 + e4 * 4] = o;
}

// Wp[dir][j][e] = bf16(W_ih)
__global__ __launch_bounds__(256) void k_cast_wih(const float* __restrict__ Wf,
                                                  const float* __restrict__ Wb,
                                                  unsigned short* __restrict__ Wp) {
  int idx = blockIdx.x * 256 + threadIdx.x;
  int dir = idx >> 20;
  int r = idx & 1048575;
  const float* src = dir ? Wb : Wf;
  float4 v = *(const float4*)&src[(size_t)r * 4];
  ushort4 o;
  o.x = f2bf(v.x); o.y = f2bf(v.y); o.z = f2bf(v.z); o.w = f2bf(v.w);
  *(ushort4*)&Wp[(size_t)dir * 4194304 + (size_t)r * 4] = o;
}

// WF: W_hh in MFMA B-fragment order, per (dir, mc) slice of 32 j-rows.
// gtid = lane(6) | f(6) | mc(7) | dir(1); f = kt*2+nt
// B[n_local = nt*16+(lane&15)][k = kt*32+(lane>>4)*8 + v], v<8
// j = (n_local>>3)*1024 + mc*8 + (n_local&7)
__global__ __launch_bounds__(256) void k_build_wf(const float* __restrict__ Wf,
                                                  const float* __restrict__ Wb,
                                                  unsigned short* __restrict__ WF) {
  int gtid = blockIdx.x * 256 + threadIdx.x;   // 2^20
  int lane = gtid & 63;
  int f    = (gtid >> 6) & 63;
  int mc   = (gtid >> 12) & 127;
  int dir  = (gtid >> 19) & 1;
  int kt = f >> 1, nt = f & 1;
  int n_local = nt * 16 + (lane & 15);
  int j = (n_local >> 3) * 1024 + mc * 8 + (n_local & 7);
  int k0 = kt * 32 + (lane >> 4) * 8;
  const float* src = dir ? Wb : Wf;
  const float* s = &src[(size_t)j * 1024 + k0];
  float4 v0 = *(const float4*)s;
  float4 v1 = *(const float4*)(s + 4);
  ushort4 oa, ob;
  oa.x = f2bf(v0.x); oa.y = f2bf(v0.y); oa.z = f2bf(v0.z); oa.w = f2bf(v0.w);
  ob.x = f2bf(v1.x); ob.y = f2bf(v1.y); ob.z = f2bf(v1.z); ob.w = f2bf(v1.w);
  *(ushort4*)&WF[(size_t)gtid * 8] = oa;
  *(ushort4*)&WF[(size_t)gtid * 8 + 4] = ob;
}

// WET[e][k] = W_emit[k][e]  (fp32)
__global__ __launch_bounds__(256) void k_build_wet(const float* __restrict__ We,
                                                   float* __restrict__ WET) {
  int idx = blockIdx.x * 256 + threadIdx.x;  // 32768
  int e = idx >> 4, k = idx & 15;
  WET[(size_t)e * 16 + k] = We[(size_t)k * 2048 + e];
}

// ---------------- projection GEMM (bf16 MFMA): P[dir][m][j] = A @ W_ih^T + b ----------------
__global__ __launch_bounds__(256) void k_proj(const unsigned short* __restrict__ A,
                                              const unsigned short* __restrict__ Wp,
                                              const float* __restrict__ bfv,
                                              const float* __restrict__ bbv,
                                              unsigned short* __restrict__ P) {
  const int dir = blockIdx.z;
  const unsigned short* Ad = A + (size_t)dir * 4194304;
  const unsigned short* Wd = Wp + (size_t)dir * 4194304;
  const float* bias = dir ? bbv : bfv;
  unsigned short* Pd = P + (size_t)dir * 16777216;
  const int bm = blockIdx.x * 128;
  const int bn = blockIdx.y * 128;
  __shared__ unsigned short As[128 * 32];
  __shared__ unsigned short Bs[128 * 32];
  const int tid = threadIdx.x;
  const int w = tid >> 6, lane = tid & 63;
  const int wm = (w >> 1) * 64, wn = (w & 1) * 64;
  const int q = lane >> 4, rr = lane & 15;

  f32x4 acc[4][4];
#pragma unroll
  for (int i = 0; i < 4; ++i)
#pragma unroll
    for (int j = 0; j < 4; ++j) acc[i][j] = (f32x4){0.f, 0.f, 0.f, 0.f};

  for (int k0 = 0; k0 < 1024; k0 += 32) {
#pragma unroll
    for (int i = 0; i < 2; ++i) {
      int c = i * 256 + tid;
      int row = c >> 2, col = (c & 3) * 8;
      const unsigned short* ga = Ad + (size_t)(bm + row) * 1024 + k0 + col;
      const unsigned short* gb = Wd + (size_t)(bn + row) * 1024 + k0 + col;
      __builtin_amdgcn_global_load_lds((const AS1 void*)ga,
                                       (AS3 void*)&As[(i * 256 + w * 64) * 8], 16, 0, 0);
      __builtin_amdgcn_global_load_lds((const AS1 void*)gb,
                                       (AS3 void*)&Bs[(i * 256 + w * 64) * 8], 16, 0, 0);
    }
    __syncthreads();
    short8 av[4], bv[4];
#pragma unroll
    for (int i = 0; i < 4; ++i)
      av[i] = *(const short8*)&As[(wm + i * 16 + rr) * 32 + q * 8];
#pragma unroll
    for (int j = 0; j < 4; ++j)
      bv[j] = *(const short8*)&Bs[(wn + j * 16 + rr) * 32 + q * 8];
#pragma unroll
    for (int i = 0; i < 4; ++i)
#pragma unroll
      for (int j = 0; j < 4; ++j)
        acc[i][j] = __builtin_amdgcn_mfma_f32_16x16x32_bf16(av[i], bv[j], acc[i][j], 0, 0, 0);
    __syncthreads();
  }
#pragma unroll
  for (int i = 0; i < 4; ++i)
#pragma unroll
    for (int j = 0; j < 4; ++j)
#pragma unroll
      for (int reg = 0; reg < 4; ++reg) {
        int row = wm + i * 16 + q * 4 + reg;
        int col = wn + j * 16 + rr;
        float vv = acc[i][j][reg] + bias[bn + col];
        Pd[(size_t)(bm + row) * 4096 + bn + col] = f2bf(vv);
      }
}

// ---------------- persistent recurrence: R5 structure + targeted fixes ----------------
// 256 blocks: dir = bid&1, mc = bid>>1 (mc<128). 32 j-rows (4 gates x 8 hidden) in LDS.
// Waves 1,2: MFMA (n-tiles 0,1), 4 independent accumulators.
// Waves 0,3: duplicate 1-cell epilogue (bitwise identical fp32).
//   wave 0: publishes hg (16 u64 agent stores, shfl-packed) -> s_waitcnt -> flag.
//   wave 3: h_seq HBM stores (off the ack path).
// h_lds stride 1032 shorts (516 words, 516%32=4): rows 0-7 hit distinct bank groups.
// LDS: w_lds 65536 B | h_lds 8x1032 shorts = 16512 B | gl 32x9 f32 = 1152 B -> 83200 B
__global__ __launch_bounds__(256, 1) void k_rec(const unsigned short* __restrict__ WF,
                                                const unsigned short* __restrict__ P,
                                                const int* __restrict__ lengths,
                                                ull* __restrict__ hg,      // [2][2][2048]
                                                uint* __restrict__ flags,  // [2dir][128]
                                                float* __restrict__ h_seq) {
  extern __shared__ char smem[];
  unsigned short* w_lds = (unsigned short*)smem;             // 32768 shorts = 65536 B
  unsigned short* h_lds = (unsigned short*)(smem + 65536);   // 8 x 1032 shorts
  float* gl = (float*)(smem + 82048);                        // 32 x 9

  const int bid = blockIdx.x;
  const int dir = bid & 1;
  const int mc  = bid >> 1;
  const int tid = threadIdx.x;
  const int w   = tid >> 6, lane = tid & 63;
  const int q   = lane >> 4;
  const int nt  = w - 1;                 // waves 1,2 -> n-tiles 0,1

  // ---- stage W slice into LDS (once): 32768 shorts = 4096 uint4 ----
  {
    const uint4* src = (const uint4*)(WF + (size_t)(dir * 128 + mc) * 32768);
    uint4* dst = (uint4*)w_lds;
#pragma unroll
    for (int r_ = 0; r_ < 16; ++r_) dst[tid + 256 * r_] = src[tid + 256 * r_];
  }

  // epilogue identity (waves 0 and 3): cell (b = lane>>3, r = lane&7)
  const bool epi = (w == 0) || (w == 3);
  const int eb = lane >> 3, er = lane & 7;
  const int len_e = epi ? lengths[eb] : 0;
  float c_reg = 0.f, h_reg = 0.f;
  uint* flg = flags + dir * 128;
  __syncthreads();

  for (int t = 0; t < 512; ++t) {
    // ---- P prefetch (raw ushorts; converted only in epilogue) ----
    unsigned short pv0 = 0, pv1 = 0, pv2 = 0, pv3 = 0;
    if (epi) {
      const unsigned short* prow =
          P + (size_t)dir * 16777216 + (size_t)(t * 8 + eb) * 4096 + mc * 8 + er;
      pv0 = prow[0]; pv1 = prow[1024]; pv2 = prow[2048]; pv3 = prow[3072];
    }

    if (t > 0) {
      // ---- wait: all 128 same-dir blocks published h[t-1] (flag >= t) ----
      if (w == 0) {
        uint need = (uint)t;
        for (;;) {
          uint a = __hip_atomic_load(&flg[lane], __ATOMIC_RELAXED, __HIP_MEMORY_SCOPE_AGENT);
          uint b2 = __hip_atomic_load(&flg[64 + lane], __ATOMIC_RELAXED, __HIP_MEMORY_SCOPE_AGENT);
          if (__ballot((a < need) || (b2 < need)) == 0ull) break;
        }
      }
      __syncthreads();                                   // B1
      // ---- bulk load h[t-1]: 2048 u64 coalesced; u -> (b = u>>8, col pair) ----
      const ull* hsrc = hg + (size_t)(((t - 1) & 1) * 2 + dir) * 2048;
#pragma unroll
      for (int r_ = 0; r_ < 8; ++r_) {
        int u = tid + 256 * r_;
        ull v = __hip_atomic_load(&hsrc[u], __ATOMIC_RELAXED, __HIP_MEMORY_SCOPE_AGENT);
        *(ull*)&h_lds[(u >> 8) * 1032 + (u & 255) * 4] = v;
      }
      __syncthreads();                                   // B2: h_lds ready
      // ---- MFMA: waves 1,2 with 4 independent accumulators ----
      if (nt == 0 || nt == 1) {
        f32x4 a0 = (f32x4){0.f,0.f,0.f,0.f}, a1 = a0, a2 = a0, a3 = a0;
#pragma unroll
        for (int kt = 0; kt < 32; kt += 4) {
          short8 v0 = *(const short8*)&h_lds[(lane & 7) * 1032 + (kt + 0) * 32 + q * 8];
          short8 v1 = *(const short8*)&h_lds[(lane & 7) * 1032 + (kt + 1) * 32 + q * 8];
          short8 v2 = *(const short8*)&h_lds[(lane & 7) * 1032 + (kt + 2) * 32 + q * 8];
          short8 v3 = *(const short8*)&h_lds[(lane & 7) * 1032 + (kt + 3) * 32 + q * 8];
          short8 b0 = *(const short8*)&w_lds[((kt + 0) * 2 + nt) * 512 + lane * 8];
          short8 b1 = *(const short8*)&w_lds[((kt + 1) * 2 + nt) * 512 + lane * 8];
          short8 b2 = *(const short8*)&w_lds[((kt + 2) * 2 + nt) * 512 + lane * 8];
          short8 b3 = *(const short8*)&w_lds[((kt + 3) * 2 + nt) * 512 + lane * 8];
          a0 = __builtin_amdgcn_mfma_f32_16x16x32_bf16(v0, b0, a0, 0, 0, 0);
          a1 = __builtin_amdgcn_mfma_f32_16x16x32_bf16(v1, b1, a1, 0, 0, 0);
          a2 = __builtin_amdgcn_mfma_f32_16x16x32_bf16(v2, b2, a2, 0, 0, 0);
          a3 = __builtin_amdgcn_mfma_f32_16x16x32_bf16(v3, b3, a3, 0, 0, 0);
        }
        a0 += a1; a2 += a3; a0 += a2;
        if (q < 2) {
#pragma unroll
          for (int reg = 0; reg < 4; ++reg)
            gl[(nt * 16 + (lane & 15)) * 9 + q * 4 + reg] = a0[reg];
        }
      }
    }
    __syncthreads();                                     // B3: gl ready (or t==0)

    // ---- epilogue: waves 0 and 3 compute identical cells ----
    if (epi) {
      if (t < len_e) {
        float g0 = (t > 0) ? gl[(0 * 8 + er) * 9 + eb] : 0.f;
        float g1 = (t > 0) ? gl[(1 * 8 + er) * 9 + eb] : 0.f;
        float g2 = (t > 0) ? gl[(2 * 8 + er) * 9 + eb] : 0.f;
        float g3 = (t > 0) ? gl[(3 * 8 + er) * 9 + eb] : 0.f;
        float gi = g0 + bfl(pv0);
        float gf = g1 + bfl(pv1);
        float gg = g2 + bfl(pv2);
        float go = g3 + bfl(pv3);
        float si = 1.f / (1.f + __expf(-gi));
        float sf = 1.f / (1.f + __expf(-gf));
        float so = 1.f / (1.f + __expf(-go));
        float tg = tanhf(gg);
        float cn = sf * c_reg + si * tg;
        float hn = so * tanhf(cn);
        c_reg = cn;
        h_reg = hn;
      }
      if (w == 3) {
        if (t < len_e)
          h_seq[((size_t)(dir * 512 + t) * 8 + eb) * 1024 + mc * 8 + er] = h_reg;
      } else {
        // wave 0: pack 4 adjacent hidden units via shfl, publish u64 (L3-bound)
        float h1 = __shfl_xor(h_reg, 1);
        uint pk = (uint)f2bf(h_reg) | ((uint)f2bf(h1) << 16);   // valid on even er
        uint pk2 = __shfl_xor(pk, 2);
        if ((lane & 3) == 0) {
          ull word = (ull)pk | ((ull)pk2 << 32);
          ull* dst = hg + (size_t)((t & 1) * 2 + dir) * 2048
                     + (size_t)eb * 256 + mc * 2 + (er >> 2);
          __hip_atomic_store(dst, word, __ATOMIC_RELAXED, __HIP_MEMORY_SCOPE_AGENT);
        }
        __builtin_amdgcn_s_waitcnt(0);      // wave 0: 16 hg stores acked at L3
        if (tid == 0)
          __hip_atomic_store(&flg[mc], (uint)(t + 1), __ATOMIC_RELAXED,
                             __HIP_MEMORY_SCOPE_AGENT);
      }
    }
  }
}

// ---------------- emissions: emit[t*8+b][k] = [hf, hb(rev)] @ W_emit^T + b_emit ----------------
__global__ __launch_bounds__(64) void k_emit(const float* __restrict__ h_seq,
    const float* __restrict__ WET, const float* __restrict__ b_emit,
    const int* __restrict__ lengths, float* __restrict__ emit) {
  __shared__ float hl[4][2048];
  const int tid = threadIdx.x;
  const int p0 = blockIdx.x * 4;
  for (int i = 0; i < 32; ++i) {
    int idx = tid + i * 64;          // float4 index 0..2047
    int pl = idx >> 9;
    int r = idx & 511;
    int p = p0 + pl;
    int t = p >> 3, b = p & 7;
    int len = lengths[b];
    float4 v = make_float4(0.f, 0.f, 0.f, 0.f);
    if (t < len) {
      if (r < 256) {
        v = *(const float4*)&h_seq[((size_t)t * 8 + b) * 1024 + r * 4];
      } else {
        int tr = len - 1 - t;
        v = *(const float4*)&h_seq[((size_t)(512 + tr) * 8 + b) * 1024 + (r - 256) * 4];
      }
    }
    *(float4*)&hl[pl][r * 4] = v;
  }
  __syncthreads();
  const int k = tid & 15, pl = tid >> 4;
  const int p = p0 + pl;
  const int t = p >> 3, b = p & 7;
  const int len = lengths[b];
  float acc = 0.f;
  if (t < len) {
    const float* hrow = hl[pl];
#pragma unroll 4
    for (int e4 = 0; e4 < 512; ++e4) {
      float4 h4 = *(const float4*)&hrow[e4 * 4];
      acc += h4.x * WET[(e4 * 4 + 0) * 16 + k]
           + h4.y * WET[(e4 * 4 + 1) * 16 + k]
           + h4.z * WET[(e4 * 4 + 2) * 16 + k]
           + h4.w * WET[(e4 * 4 + 3) * 16 + k];
    }
    acc += b_emit[k];
  }
  emit[(size_t)p * 16 + k] = (t < len) ? acc : 0.f;
}

// ---------------- CRF: gold score + forward algorithm, out[b] = logZ - total ----------------
__global__ __launch_bounds__(128) void k_crf(const float* __restrict__ emit,
    const int* __restrict__ tags, const int* __restrict__ lengths,
    const float* __restrict__ trans, float* __restrict__ out) {
  __shared__ float d_lds[8][17];
  __shared__ float tot[8][17];
  __shared__ float totb[8];
  const int tid = threadIdx.x;
  const int b = tid >> 4, k = tid & 15;
  const int len = lengths[b];

  float part = 0.f;
  for (int t = k; t < 512; t += 16) {
    if (t < len) {
      int tg = tags[b * 512 + t];
      part += emit[((size_t)t * 8 + b) * 16 + tg];
      if (t >= 1) part += trans[tags[b * 512 + t - 1] * 16 + tg];
    }
  }
  tot[b][k] = part;

  float trc[16];
#pragma unroll
  for (int i = 0; i < 16; ++i) trc[i] = trans[i * 16 + k];
  d_lds[b][k] = emit[b * 16 + k];
  __syncthreads();
  if (k == 0) {
    float s = 0.f;
    for (int i = 0; i < 16; ++i) s += tot[b][i];
    totb[b] = s;
  }
  __syncthreads();

  for (int t = 1; t < 512; ++t) {
    float nd = 0.f;
    bool upd = (t < len);
    if (upd) {
      float mx = -3.0e38f;
      float v[16];
#pragma unroll
      for (int i = 0; i < 16; ++i) { v[i] = d_lds[b][i] + trc[i]; mx = fmaxf(mx, v[i]); }
      float s = 0.f;
#pragma unroll
      for (int i = 0; i < 16; ++i) s += __expf(v[i] - mx);
      nd = mx + __logf(s) + emit[((size_t)t * 8 + b) * 16 + k];
    }
    __syncthreads();
    if (upd) d_lds[b][k] = nd;
    __syncthreads();
  }

  if (k == 0) {
    float mx = -3.0e38f;
    for (int i = 0; i < 16; ++i) mx = fmaxf(mx, d_lds[b][i]);
    float s = 0.f;
    for (int i = 0; i < 16; ++i) s += __expf(d_lds[b][i] - mx);
    out[b] = (mx + __logf(s)) - totb[b];
  }
}

extern "C" void kernel_launch(void* const* d_in, const int* in_sizes, int n_in,
                              void* d_out, int out_size, void* d_ws, size_t ws_size,
                              hipStream_t stream) {
  const float* x       = (const float*)d_in[0];
  const int*   tags    = (const int*)d_in[1];
  const int*   lengths = (const int*)d_in[2];
  const float* W_ih_f  = (const float*)d_in[3];
  const float* W_hh_f  = (const float*)d_in[4];
  const float* b_f     = (const float*)d_in[5];
  const float* W_ih_b  = (const float*)d_in[6];
  const float* W_hh_b  = (const float*)d_in[7];
  const float* b_b     = (const float*)d_in[8];
  const float* W_emit  = (const float*)d_in[9];
  const float* b_emit  = (const float*)d_in[10];
  const float* trans   = (const float*)d_in[11];
  float* out = (float*)d_out;
  (void)in_sizes; (void)n_in; (void)out_size; (void)ws_size;

  char* ws = (char*)d_ws;
  unsigned short* A    = (unsigned short*)ws; ws += 16777216;   // 2 x 4096 x 1024 bf16
  unsigned short* Wp   = (unsigned short*)ws; ws += 16777216;   // 2 x 4096 x 1024 bf16
  unsigned short* WF   = (unsigned short*)ws; ws += 16777216;   // MFMA-frag-ordered W_hh
  unsigned short* P    = (unsigned short*)ws; ws += 67108864;   // 2 x 4096 x 4096 bf16
  float* h_seq = (float*)ws; ws += 33554432;                    // 2 x 512 x 8 x 1024 f32
  ull*   hg    = (ull*)ws;   ws += 65536;                       // 2buf x 2dir x 2048 u64
  uint*  flags = (uint*)ws;  ws += 4096;                        // [2][128] + pad
  float* emit  = (float*)ws; ws += 262144;
  float* WET   = (float*)ws; ws += 131072;

  static int attr_done = 0;
  if (!attr_done) {
    hipFuncSetAttribute((const void*)k_rec,
                        hipFuncAttributeMaxDynamicSharedMemorySize, 83200);
    attr_done = 1;
  }

  hipMemsetAsync(flags, 0, 4096, stream);
  k_build_A<<<8192, 256, 0, stream>>>(x, lengths, A);
  k_cast_wih<<<8192, 256, 0, stream>>>(W_ih_f, W_ih_b, Wp);
  k_build_wf<<<4096, 256, 0, stream>>>(W_hh_f, W_hh_b, WF);
  k_build_wet<<<128, 256, 0, stream>>>(W_emit, WET);
  k_proj<<<dim3(32, 32, 2), 256, 0, stream>>>(A, Wp, b_f, b_b, P);

  {
    const unsigned short* wf = WF;
    const unsigned short* pp = P;
    const int* ll = lengths;
    ull* hgp = hg; uint* fl = flags; float* hs = h_seq;
    void* args[] = { &wf, &pp, &ll, &hgp, &fl, &hs };
    hipLaunchCooperativeKernel((const void*)k_rec, dim3(256), dim3(256),
                               args, 83200, stream);
  }

  k_emit<<<1024, 64, 0, stream>>>(h_seq, WET, b_emit, lengths, emit);
  k_crf<<<1, 128, 0, stream>>>(emit, tags, lengths, trans, out);
}

// Round 10
// 2744.930 us; speedup vs baseline: 1.6124x; 1.0726x over previous
//
#include <hip/hip_runtime.h>
#include <hip/hip_cooperative_groups.h>
#include <stdint.h>

typedef unsigned int uint;
typedef unsigned long long ull;
typedef __attribute__((ext_vector_type(8))) short short8;
typedef __attribute__((ext_vector_type(4))) float f32x4;

#define AS1 __attribute__((address_space(1)))
#define AS3 __attribute__((address_space(3)))

__device__ __forceinline__ unsigned short f2bf(float f) {
  uint u = __float_as_uint(f);
  u += 0x7fffu + ((u >> 16) & 1u);
  return (unsigned short)(u >> 16);
}
__device__ __forceinline__ float bfl(unsigned short s) {
  return __uint_as_float(((uint)s) << 16);
}

// ---------------- build kernels ----------------

// A[dir][m=t*8+b][e] = bf16(x or x_rev), 2 x 4096 x 1024
__global__ __launch_bounds__(256) void k_build_A(const float* __restrict__ x,
                                                 const int* __restrict__ lengths,
                                                 unsigned short* __restrict__ A) {
  int idx = blockIdx.x * 256 + threadIdx.x;   // float4 units, 2*1Mi total
  int dir = idx >> 20;
  int r = idx & 1048575;
  int m = r >> 8;
  int e4 = r & 255;
  int t = m >> 3, b = m & 7;
  int st = t;
  if (dir) { int len = lengths[b]; st = (t < len) ? (len - 1 - t) : t; }
  float4 v = *(const float4*)&x[((size_t)b * 512 + st) * 1024 + e4 * 4];
  ushort4 o;
  o.x = f2bf(v.x); o.y = f2bf(v.y); o.z = f2bf(v.z); o.w = f2bf(v.w);
  *(ushort4*)&A[(size_t)dir * 4194304 + (size_t)m * 1024 + e4 * 4] = o;
}

// Wp[dir][j][e] = bf16(W_ih)
__global__ __launch_bounds__(256) void k_cast_wih(const float* __restrict__ Wf,
                                                  const float* __restrict__ Wb,
                                                  unsigned short* __restrict__ Wp) {
  int idx = blockIdx.x * 256 + threadIdx.x;
  int dir = idx >> 20;
  int r = idx & 1048575;
  const float* src = dir ? Wb : Wf;
  float4 v = *(const float4*)&src[(size_t)r * 4];
  ushort4 o;
  o.x = f2bf(v.x); o.y = f2bf(v.y); o.z = f2bf(v.z); o.w = f2bf(v.w);
  *(ushort4*)&Wp[(size_t)dir * 4194304 + (size_t)r * 4] = o;
}

// WF: W_hh in MFMA B-fragment order, per (dir, mc) slice of 32 j-rows.
// gtid = lane(6) | f(6) | mc(7) | dir(1); f = kt*2+nt
// B[n_local = nt*16+(lane&15)][k = kt*32+(lane>>4)*8 + v], v<8
// j = (n_local>>3)*1024 + mc*8 + (n_local&7)
__global__ __launch_bounds__(256) void k_build_wf(const float* __restrict__ Wf,
                                                  const float* __restrict__ Wb,
                                                  unsigned short* __restrict__ WF) {
  int gtid = blockIdx.x * 256 + threadIdx.x;   // 2^20
  int lane = gtid & 63;
  int f    = (gtid >> 6) & 63;
  int mc   = (gtid >> 12) & 127;
  int dir  = (gtid >> 19) & 1;
  int kt = f >> 1, nt = f & 1;
  int n_local = nt * 16 + (lane & 15);
  int j = (n_local >> 3) * 1024 + mc * 8 + (n_local & 7);
  int k0 = kt * 32 + (lane >> 4) * 8;
  const float* src = dir ? Wb : Wf;
  const float* s = &src[(size_t)j * 1024 + k0];
  float4 v0 = *(const float4*)s;
  float4 v1 = *(const float4*)(s + 4);
  ushort4 oa, ob;
  oa.x = f2bf(v0.x); oa.y = f2bf(v0.y); oa.z = f2bf(v0.z); oa.w = f2bf(v0.w);
  ob.x = f2bf(v1.x); ob.y = f2bf(v1.y); ob.z = f2bf(v1.z); ob.w = f2bf(v1.w);
  *(ushort4*)&WF[(size_t)gtid * 8] = oa;
  *(ushort4*)&WF[(size_t)gtid * 8 + 4] = ob;
}

// WET[e][k] = W_emit[k][e]  (fp32)
__global__ __launch_bounds__(256) void k_build_wet(const float* __restrict__ We,
                                                   float* __restrict__ WET) {
  int idx = blockIdx.x * 256 + threadIdx.x;  // 32768
  int e = idx >> 4, k = idx & 15;
  WET[(size_t)e * 16 + k] = We[(size_t)k * 2048 + e];
}

// ---------------- projection GEMM (bf16 MFMA): P[dir][m][j] = A @ W_ih^T + b ----------------
__global__ __launch_bounds__(256) void k_proj(const unsigned short* __restrict__ A,
                                              const unsigned short* __restrict__ Wp,
                                              const float* __restrict__ bfv,
                                              const float* __restrict__ bbv,
                                              unsigned short* __restrict__ P) {
  const int dir = blockIdx.z;
  const unsigned short* Ad = A + (size_t)dir * 4194304;
  const unsigned short* Wd = Wp + (size_t)dir * 4194304;
  const float* bias = dir ? bbv : bfv;
  unsigned short* Pd = P + (size_t)dir * 16777216;
  const int bm = blockIdx.x * 128;
  const int bn = blockIdx.y * 128;
  __shared__ unsigned short As[128 * 32];
  __shared__ unsigned short Bs[128 * 32];
  const int tid = threadIdx.x;
  const int w = tid >> 6, lane = tid & 63;
  const int wm = (w >> 1) * 64, wn = (w & 1) * 64;
  const int q = lane >> 4, rr = lane & 15;

  f32x4 acc[4][4];
#pragma unroll
  for (int i = 0; i < 4; ++i)
#pragma unroll
    for (int j = 0; j < 4; ++j) acc[i][j] = (f32x4){0.f, 0.f, 0.f, 0.f};

  for (int k0 = 0; k0 < 1024; k0 += 32) {
#pragma unroll
    for (int i = 0; i < 2; ++i) {
      int c = i * 256 + tid;
      int row = c >> 2, col = (c & 3) * 8;
      const unsigned short* ga = Ad + (size_t)(bm + row) * 1024 + k0 + col;
      const unsigned short* gb = Wd + (size_t)(bn + row) * 1024 + k0 + col;
      __builtin_amdgcn_global_load_lds((const AS1 void*)ga,
                                       (AS3 void*)&As[(i * 256 + w * 64) * 8], 16, 0, 0);
      __builtin_amdgcn_global_load_lds((const AS1 void*)gb,
                                       (AS3 void*)&Bs[(i * 256 + w * 64) * 8], 16, 0, 0);
    }
    __syncthreads();
    short8 av[4], bv[4];
#pragma unroll
    for (int i = 0; i < 4; ++i)
      av[i] = *(const short8*)&As[(wm + i * 16 + rr) * 32 + q * 8];
#pragma unroll
    for (int j = 0; j < 4; ++j)
      bv[j] = *(const short8*)&Bs[(wn + j * 16 + rr) * 32 + q * 8];
#pragma unroll
    for (int i = 0; i < 4; ++i)
#pragma unroll
      for (int j = 0; j < 4; ++j)
        acc[i][j] = __builtin_amdgcn_mfma_f32_16x16x32_bf16(av[i], bv[j], acc[i][j], 0, 0, 0);
    __syncthreads();
  }
#pragma unroll
  for (int i = 0; i < 4; ++i)
#pragma unroll
    for (int j = 0; j < 4; ++j)
#pragma unroll
      for (int reg = 0; reg < 4; ++reg) {
        int row = wm + i * 16 + q * 4 + reg;
        int col = wn + j * 16 + rr;
        float vv = acc[i][j][reg] + bias[bn + col];
        Pd[(size_t)(bm + row) * 4096 + bn + col] = f2bf(vv);
      }
}

// ---------------- persistent recurrence: R9 + line-private L3 sync structures ----------
// 256 blocks: dir = bid&1, mc = bid>>1 (mc<128). 32 j-rows (4 gates x 8 hidden) in LDS.
// Waves 1,2: MFMA (n-tiles 0,1), 4 independent accumulators.
// Waves 0,3: duplicate 1-cell epilogue. wave 0: hg publish + ack + flag; wave 3: h_seq.
// hg BLOCK-MAJOR: hg[buf][dir][mc*16 + eb*2 + half] -> each producer writes one
//   contiguous 128 B (2 private 64-B lines). half = er>>2 selects hidden 4-group.
// flags PADDED: one 64-B line per flag (stride 16 u32) -> no false sharing.
// h_lds stride 1032 shorts; staging unscrambles block-major -> (eb, hidden) layout.
__global__ __launch_bounds__(256, 1) void k_rec(const unsigned short* __restrict__ WF,
                                                const unsigned short* __restrict__ P,
                                                const int* __restrict__ lengths,
                                                ull* __restrict__ hg,      // [2][2][2048] block-major
                                                uint* __restrict__ flags,  // [2dir][128*16]
                                                float* __restrict__ h_seq) {
  extern __shared__ char smem[];
  unsigned short* w_lds = (unsigned short*)smem;             // 32768 shorts = 65536 B
  unsigned short* h_lds = (unsigned short*)(smem + 65536);   // 8 x 1032 shorts
  float* gl = (float*)(smem + 82048);                        // 32 x 9

  const int bid = blockIdx.x;
  const int dir = bid & 1;
  const int mc  = bid >> 1;
  const int tid = threadIdx.x;
  const int w   = tid >> 6, lane = tid & 63;
  const int q   = lane >> 4;
  const int nt  = w - 1;                 // waves 1,2 -> n-tiles 0,1

  // ---- stage W slice into LDS (once): 32768 shorts = 4096 uint4 ----
  {
    const uint4* src = (const uint4*)(WF + (size_t)(dir * 128 + mc) * 32768);
    uint4* dst = (uint4*)w_lds;
#pragma unroll
    for (int r_ = 0; r_ < 16; ++r_) dst[tid + 256 * r_] = src[tid + 256 * r_];
  }

  // epilogue identity (waves 0 and 3): cell (b = lane>>3, r = lane&7)
  const bool epi = (w == 0) || (w == 3);
  const int eb = lane >> 3, er = lane & 7;
  const int len_e = epi ? lengths[eb] : 0;
  float c_reg = 0.f, h_reg = 0.f;
  uint* flg = flags + dir * 2048;        // 128 flags x 16-u32 stride
  __syncthreads();

  for (int t = 0; t < 512; ++t) {
    // ---- P prefetch (raw ushorts; converted only in epilogue) ----
    unsigned short pv0 = 0, pv1 = 0, pv2 = 0, pv3 = 0;
    if (epi) {
      const unsigned short* prow =
          P + (size_t)dir * 16777216 + (size_t)(t * 8 + eb) * 4096 + mc * 8 + er;
      pv0 = prow[0]; pv1 = prow[1024]; pv2 = prow[2048]; pv3 = prow[3072];
    }

    if (t > 0) {
      // ---- wait: all 128 same-dir blocks published h[t-1] (flag >= t) ----
      if (w == 0) {
        uint need = (uint)t;
        for (;;) {
          uint a = __hip_atomic_load(&flg[lane << 4], __ATOMIC_RELAXED,
                                     __HIP_MEMORY_SCOPE_AGENT);
          uint b2 = __hip_atomic_load(&flg[(64 + lane) << 4], __ATOMIC_RELAXED,
                                      __HIP_MEMORY_SCOPE_AGENT);
          if (__ballot((a < need) || (b2 < need)) == 0ull) break;
        }
      }
      __syncthreads();                                   // B1
      // ---- bulk load h[t-1]: 2048 u64 coalesced (block-major), unscramble ----
      const ull* hsrc = hg + (size_t)(((t - 1) & 1) * 2 + dir) * 2048;
#pragma unroll
      for (int r_ = 0; r_ < 8; ++r_) {
        int u = tid + 256 * r_;
        ull v = __hip_atomic_load(&hsrc[u], __ATOMIC_RELAXED, __HIP_MEMORY_SCOPE_AGENT);
        int pmc = u >> 4;                 // producer block
        int low = u & 15;
        int peb = low >> 1, phalf = low & 1;
        *(ull*)&h_lds[peb * 1032 + pmc * 8 + phalf * 4] = v;
      }
      __syncthreads();                                   // B2: h_lds ready
      // ---- MFMA: waves 1,2 with 4 independent accumulators ----
      if (nt == 0 || nt == 1) {
        f32x4 a0 = (f32x4){0.f,0.f,0.f,0.f}, a1 = a0, a2 = a0, a3 = a0;
#pragma unroll
        for (int kt = 0; kt < 32; kt += 4) {
          short8 v0 = *(const short8*)&h_lds[(lane & 7) * 1032 + (kt + 0) * 32 + q * 8];
          short8 v1 = *(const short8*)&h_lds[(lane & 7) * 1032 + (kt + 1) * 32 + q * 8];
          short8 v2 = *(const short8*)&h_lds[(lane & 7) * 1032 + (kt + 2) * 32 + q * 8];
          short8 v3 = *(const short8*)&h_lds[(lane & 7) * 1032 + (kt + 3) * 32 + q * 8];
          short8 b0 = *(const short8*)&w_lds[((kt + 0) * 2 + nt) * 512 + lane * 8];
          short8 b1 = *(const short8*)&w_lds[((kt + 1) * 2 + nt) * 512 + lane * 8];
          short8 b2 = *(const short8*)&w_lds[((kt + 2) * 2 + nt) * 512 + lane * 8];
          short8 b3 = *(const short8*)&w_lds[((kt + 3) * 2 + nt) * 512 + lane * 8];
          a0 = __builtin_amdgcn_mfma_f32_16x16x32_bf16(v0, b0, a0, 0, 0, 0);
          a1 = __builtin_amdgcn_mfma_f32_16x16x32_bf16(v1, b1, a1, 0, 0, 0);
          a2 = __builtin_amdgcn_mfma_f32_16x16x32_bf16(v2, b2, a2, 0, 0, 0);
          a3 = __builtin_amdgcn_mfma_f32_16x16x32_bf16(v3, b3, a3, 0, 0, 0);
        }
        a0 += a1; a2 += a3; a0 += a2;
        if (q < 2) {
#pragma unroll
          for (int reg = 0; reg < 4; ++reg)
            gl[(nt * 16 + (lane & 15)) * 9 + q * 4 + reg] = a0[reg];
        }
      }
    }
    __syncthreads();                                     // B3: gl ready (or t==0)

    // ---- epilogue: waves 0 and 3 compute identical cells ----
    if (epi) {
      if (t < len_e) {
        float g0 = (t > 0) ? gl[(0 * 8 + er) * 9 + eb] : 0.f;
        float g1 = (t > 0) ? gl[(1 * 8 + er) * 9 + eb] : 0.f;
        float g2 = (t > 0) ? gl[(2 * 8 + er) * 9 + eb] : 0.f;
        float g3 = (t > 0) ? gl[(3 * 8 + er) * 9 + eb] : 0.f;
        float gi = g0 + bfl(pv0);
        float gf = g1 + bfl(pv1);
        float gg = g2 + bfl(pv2);
        float go = g3 + bfl(pv3);
        float si = 1.f / (1.f + __expf(-gi));
        float sf = 1.f / (1.f + __expf(-gf));
        float so = 1.f / (1.f + __expf(-go));
        float tg = tanhf(gg);
        float cn = sf * c_reg + si * tg;
        float hn = so * tanhf(cn);
        c_reg = cn;
        h_reg = hn;
      }
      if (w == 3) {
        if (t < len_e)
          h_seq[((size_t)(dir * 512 + t) * 8 + eb) * 1024 + mc * 8 + er] = h_reg;
      } else {
        // wave 0: pack 4 adjacent hidden units via shfl; publish into the block's
        // private 128-B chunk (2 cache lines): dst = mc*16 + eb*2 + (er>>2)
        float h1 = __shfl_xor(h_reg, 1);
        uint pk = (uint)f2bf(h_reg) | ((uint)f2bf(h1) << 16);   // valid on even er
        uint pk2 = __shfl_xor(pk, 2);
        if ((lane & 3) == 0) {
          ull word = (ull)pk | ((ull)pk2 << 32);
          ull* dst = hg + (size_t)((t & 1) * 2 + dir) * 2048
                     + (size_t)mc * 16 + eb * 2 + (er >> 2);
          __hip_atomic_store(dst, word, __ATOMIC_RELAXED, __HIP_MEMORY_SCOPE_AGENT);
        }
        __builtin_amdgcn_s_waitcnt(0);      // wave 0: 16 hg stores acked at L3
        if (tid == 0)
          __hip_atomic_store(&flg[mc << 4], (uint)(t + 1), __ATOMIC_RELAXED,
                             __HIP_MEMORY_SCOPE_AGENT);
      }
    }
  }
}

// ---------------- emissions: emit[t*8+b][k] = [hf, hb(rev)] @ W_emit^T + b_emit ----------------
__global__ __launch_bounds__(64) void k_emit(const float* __restrict__ h_seq,
    const float* __restrict__ WET, const float* __restrict__ b_emit,
    const int* __restrict__ lengths, float* __restrict__ emit) {
  __shared__ float hl[4][2048];
  const int tid = threadIdx.x;
  const int p0 = blockIdx.x * 4;
  for (int i = 0; i < 32; ++i) {
    int idx = tid + i * 64;          // float4 index 0..2047
    int pl = idx >> 9;
    int r = idx & 511;
    int p = p0 + pl;
    int t = p >> 3, b = p & 7;
    int len = lengths[b];
    float4 v = make_float4(0.f, 0.f, 0.f, 0.f);
    if (t < len) {
      if (r < 256) {
        v = *(const float4*)&h_seq[((size_t)t * 8 + b) * 1024 + r * 4];
      } else {
        int tr = len - 1 - t;
        v = *(const float4*)&h_seq[((size_t)(512 + tr) * 8 + b) * 1024 + (r - 256) * 4];
      }
    }
    *(float4*)&hl[pl][r * 4] = v;
  }
  __syncthreads();
  const int k = tid & 15, pl = tid >> 4;
  const int p = p0 + pl;
  const int t = p >> 3, b = p & 7;
  const int len = lengths[b];
  float acc = 0.f;
  if (t < len) {
    const float* hrow = hl[pl];
#pragma unroll 4
    for (int e4 = 0; e4 < 512; ++e4) {
      float4 h4 = *(const float4*)&hrow[e4 * 4];
      acc += h4.x * WET[(e4 * 4 + 0) * 16 + k]
           + h4.y * WET[(e4 * 4 + 1) * 16 + k]
           + h4.z * WET[(e4 * 4 + 2) * 16 + k]
           + h4.w * WET[(e4 * 4 + 3) * 16 + k];
    }
    acc += b_emit[k];
  }
  emit[(size_t)p * 16 + k] = (t < len) ? acc : 0.f;
}

// ---------------- CRF: gold score + forward algorithm, out[b] = logZ - total ----------------
__global__ __launch_bounds__(128) void k_crf(const float* __restrict__ emit,
    const int* __restrict__ tags, const int* __restrict__ lengths,
    const float* __restrict__ trans, float* __restrict__ out) {
  __shared__ float d_lds[8][17];
  __shared__ float tot[8][17];
  __shared__ float totb[8];
  const int tid = threadIdx.x;
  const int b = tid >> 4, k = tid & 15;
  const int len = lengths[b];

  float part = 0.f;
  for (int t = k; t < 512; t += 16) {
    if (t < len) {
      int tg = tags[b * 512 + t];
      part += emit[((size_t)t * 8 + b) * 16 + tg];
      if (t >= 1) part += trans[tags[b * 512 + t - 1] * 16 + tg];
    }
  }
  tot[b][k] = part;

  float trc[16];
#pragma unroll
  for (int i = 0; i < 16; ++i) trc[i] = trans[i * 16 + k];
  d_lds[b][k] = emit[b * 16 + k];
  __syncthreads();
  if (k == 0) {
    float s = 0.f;
    for (int i = 0; i < 16; ++i) s += tot[b][i];
    totb[b] = s;
  }
  __syncthreads();

  for (int t = 1; t < 512; ++t) {
    float nd = 0.f;
    bool upd = (t < len);
    if (upd) {
      float mx = -3.0e38f;
      float v[16];
#pragma unroll
      for (int i = 0; i < 16; ++i) { v[i] = d_lds[b][i] + trc[i]; mx = fmaxf(mx, v[i]); }
      float s = 0.f;
#pragma unroll
      for (int i = 0; i < 16; ++i) s += __expf(v[i] - mx);
      nd = mx + __logf(s) + emit[((size_t)t * 8 + b) * 16 + k];
    }
    __syncthreads();
    if (upd) d_lds[b][k] = nd;
    __syncthreads();
  }

  if (k == 0) {
    float mx = -3.0e38f;
    for (int i = 0; i < 16; ++i) mx = fmaxf(mx, d_lds[b][i]);
    float s = 0.f;
    for (int i = 0; i < 16; ++i) s += __expf(d_lds[b][i] - mx);
    out[b] = (mx + __logf(s)) - totb[b];
  }
}

extern "C" void kernel_launch(void* const* d_in, const int* in_sizes, int n_in,
                              void* d_out, int out_size, void* d_ws, size_t ws_size,
                              hipStream_t stream) {
  const float* x       = (const float*)d_in[0];
  const int*   tags    = (const int*)d_in[1];
  const int*   lengths = (const int*)d_in[2];
  const float* W_ih_f  = (const float*)d_in[3];
  const float* W_hh_f  = (const float*)d_in[4];
  const float* b_f     = (const float*)d_in[5];
  const float* W_ih_b  = (const float*)d_in[6];
  const float* W_hh_b  = (const float*)d_in[7];
  const float* b_b     = (const float*)d_in[8];
  const float* W_emit  = (const float*)d_in[9];
  const float* b_emit  = (const float*)d_in[10];
  const float* trans   = (const float*)d_in[11];
  float* out = (float*)d_out;
  (void)in_sizes; (void)n_in; (void)out_size; (void)ws_size;

  char* ws = (char*)d_ws;
  unsigned short* A    = (unsigned short*)ws; ws += 16777216;   // 2 x 4096 x 1024 bf16
  unsigned short* Wp   = (unsigned short*)ws; ws += 16777216;   // 2 x 4096 x 1024 bf16
  unsigned short* WF   = (unsigned short*)ws; ws += 16777216;   // MFMA-frag-ordered W_hh
  unsigned short* P    = (unsigned short*)ws; ws += 67108864;   // 2 x 4096 x 4096 bf16
  float* h_seq = (float*)ws; ws += 33554432;                    // 2 x 512 x 8 x 1024 f32
  ull*   hg    = (ull*)ws;   ws += 65536;                       // 2buf x 2dir x 2048 u64
  uint*  flags = (uint*)ws;  ws += 16384;                       // 2dir x 128 x 64B lines
  float* emit  = (float*)ws; ws += 262144;
  float* WET   = (float*)ws; ws += 131072;

  static int attr_done = 0;
  if (!attr_done) {
    hipFuncSetAttribute((const void*)k_rec,
                        hipFuncAttributeMaxDynamicSharedMemorySize, 83200);
    attr_done = 1;
  }

  hipMemsetAsync(flags, 0, 16384, stream);
  k_build_A<<<8192, 256, 0, stream>>>(x, lengths, A);
  k_cast_wih<<<8192, 256, 0, stream>>>(W_ih_f, W_ih_b, Wp);
  k_build_wf<<<4096, 256, 0, stream>>>(W_hh_f, W_hh_b, WF);
  k_build_wet<<<128, 256, 0, stream>>>(W_emit, WET);
  k_proj<<<dim3(32, 32, 2), 256, 0, stream>>>(A, Wp, b_f, b_b, P);

  {
    const unsigned short* wf = WF;
    const unsigned short* pp = P;
    const int* ll = lengths;
    ull* hgp = hg; uint* fl = flags; float* hs = h_seq;
    void* args[] = { &wf, &pp, &ll, &hgp, &fl, &hs };
    hipLaunchCooperativeKernel((const void*)k_rec, dim3(256), dim3(256),
                               args, 83200, stream);
  }

  k_emit<<<1024, 64, 0, stream>>>(h_seq, WET, b_emit, lengths, emit);
  k_crf<<<1, 128, 0, stream>>>(emit, tags, lengths, trans, out);
}